// Round 3
// baseline (291.432 us; speedup 1.0000x reference)
//
#include <hip/hip_runtime.h>

#define HWD (512*512)
#define Wd 512
#define Hd 512
#define Cd 256
#define Kd 21
#define Nd 2560

// ---------------------------------------------------------------------------
// Event-list build (3 tiny kernels).  An "event" is a box edge at integral
// row r: at r = y1-1 the box contributes +(S[r][x1-1]-S[r][x0-1]); at
// r = y0-1 (if y0>0) it contributes the negative.  Events are bucketed per
// row so the fused scan kernel can consume corners as it streams past.
// Packing: ev = n (12b) | row<<12 (9b) | sign<<31.
// ---------------------------------------------------------------------------
__global__ __launch_bounds__(512) void k_zero(int* __restrict__ cnt) {
    cnt[threadIdx.x] = 0;
}

__global__ __launch_bounds__(256) void k_count(const int* __restrict__ boxes,
                                               int* __restrict__ cnt) {
    const int n = blockIdx.x * 256 + threadIdx.x;
    if (n >= Nd) return;
    const int y0 = boxes[n * 4 + 1];
    const int y1 = boxes[n * 4 + 3];
    if (y0 > 0) atomicAdd(&cnt[y0 - 1], 1);
    atomicAdd(&cnt[y1 - 1], 1);
}

__global__ __launch_bounds__(512) void k_scan(const int* __restrict__ cnt,
                                              int* __restrict__ start,
                                              int* __restrict__ cursor) {
    const int t = threadIdx.x, lane = t & 63, wv = t >> 6;
    const int v = cnt[t];
    int inc = v;
    #pragma unroll
    for (int d = 1; d < 64; d <<= 1) {
        int u = __shfl_up(inc, d);
        if (lane >= d) inc += u;
    }
    __shared__ int tt[8];
    if (lane == 63) tt[wv] = inc;
    __syncthreads();
    int off = 0;
    #pragma unroll
    for (int w = 0; w < 8; ++w)
        if (w < wv) off += tt[w];
    inc += off;
    start[t]  = inc - v;     // exclusive prefix
    cursor[t] = inc - v;
    if (t == 511) start[512] = inc;   // total
}

__global__ __launch_bounds__(256) void k_scatter(const int* __restrict__ boxes,
                                                 int* __restrict__ cursor,
                                                 unsigned int* __restrict__ ev) {
    const int n = blockIdx.x * 256 + threadIdx.x;
    if (n >= Nd) return;
    const int y0 = boxes[n * 4 + 1];
    const int y1 = boxes[n * 4 + 3];
    if (y0 > 0) {
        int r = y0 - 1;
        int p = atomicAdd(&cursor[r], 1);
        ev[p] = (unsigned int)n | ((unsigned int)r << 12) | 0x80000000u;
    }
    {
        int r = y1 - 1;
        int p = atomicAdd(&cursor[r], 1);
        ev[p] = (unsigned int)n | ((unsigned int)r << 12);
    }
}

// ---------------------------------------------------------------------------
// Fused integral + ROI pool.  One block per channel (256 blocks = 1/CU),
// 512 threads, thread owns column x.  Streams the channel in 8-row slabs:
//   - 8 independent wave-shfl row scans (ILP) + cross-wave LDS offsets
//   - serial y accumulation in a register (acc) -> integral values
//   - 8-row integral slab kept in LDS (double-buffered)
//   - per-row box-edge events consume corners from the slab into partial[n]
// The 268MB integral is NEVER written to global.  Race-free without atomics:
// a box's two events are >= bh >= 8 rows apart, so they never land in the
// same aligned 8-row window; distinct boxes touch distinct partial slots.
// ---------------------------------------------------------------------------
__global__ __launch_bounds__(512) void k_ipool(const float* __restrict__ f,
                                               const int* __restrict__ boxes,
                                               const int* __restrict__ ev_start,
                                               const unsigned int* __restrict__ ev_list,
                                               float* __restrict__ pool) {
    const int c = blockIdx.x;
    const int x = threadIdx.x;
    const int lane = x & 63, wv = x >> 6;
    const float* F = f + (size_t)c * HWD;

    __shared__ float S[2][8][512];      // 32 KB: integral slab (double-buffered)
    __shared__ float tot[2][8][8];      // wave totals per row
    __shared__ float partial[Nd];       // 10 KB: per-box accumulated sum

    for (int n = x; n < Nd; n += 512) partial[n] = 0.f;
    // (ordered before any event processing by the first __syncthreads below)

    float acc = 0.f;
    float cur[8];
    #pragma unroll
    for (int j = 0; j < 8; ++j) cur[j] = F[(size_t)j * Wd + x];

    for (int yb = 0; yb < Hd; yb += 8) {
        const int buf = (yb >> 3) & 1;
        float nxt[8];
        const bool more = (yb + 8 < Hd);
        if (more) {
            #pragma unroll
            for (int j = 0; j < 8; ++j) nxt[j] = F[(size_t)(yb + 8 + j) * Wd + x];
        }

        // 8 independent wave-inclusive scans
        float r[8];
        #pragma unroll
        for (int j = 0; j < 8; ++j) r[j] = cur[j];
        #pragma unroll
        for (int d = 1; d < 64; d <<= 1) {
            #pragma unroll
            for (int j = 0; j < 8; ++j) {
                float t = __shfl_up(r[j], d);
                if (lane >= d) r[j] += t;
            }
        }
        if (lane == 63) {
            #pragma unroll
            for (int j = 0; j < 8; ++j) tot[buf][j][wv] = r[j];
        }
        __syncthreads();

        // cross-wave offsets + serial y accumulation -> integral slab
        #pragma unroll
        for (int j = 0; j < 8; ++j) {
            float off = 0.f;
            #pragma unroll
            for (int w = 0; w < 8; ++w)
                if (w < wv) off += tot[buf][j][w];
            acc += r[j] + off;
            S[buf][j][x] = acc;
        }
        __syncthreads();

        // consume this slab's box-edge events
        const int e0 = ev_start[yb];
        const int e1 = ev_start[yb + 8];
        for (int e = e0 + x; e < e1; e += 512) {
            const unsigned int ev = ev_list[e];
            const int n   = ev & 0xFFF;
            const int row = (ev >> 12) & 0x1FF;
            const int x0  = boxes[n * 4 + 0];
            const int x1  = boxes[n * 4 + 2];
            const float sx1 = S[buf][row & 7][x1 - 1];
            const float sx0 = (x0 > 0) ? S[buf][row & 7][x0 - 1] : 0.f;
            float d = sx1 - sx0;
            partial[n] += (ev & 0x80000000u) ? -d : d;
        }

        if (more) {
            #pragma unroll
            for (int j = 0; j < 8; ++j) cur[j] = nxt[j];
        }
    }
    __syncthreads();

    // write this channel's column of pool
    for (int n = x; n < Nd; n += 512) {
        const int x0 = boxes[n * 4 + 0];
        const int y0 = boxes[n * 4 + 1];
        const int x1 = boxes[n * 4 + 2];
        const int y1 = boxes[n * 4 + 3];
        const float area = (float)((x1 - x0) * (y1 - y0));
        pool[(size_t)n * Cd + c] = partial[n] / area;
    }
}

// ---------------------------------------------------------------------------
// Argmax over K=21 classes per pixel -> u8 map.  First-max-wins (strict >).
// ---------------------------------------------------------------------------
__global__ __launch_bounds__(256) void k_argmax(const float* __restrict__ ncb,
                                                unsigned char* __restrict__ map) {
    const int p = blockIdx.x * 256 + threadIdx.x;
    float best = ncb[p];
    int bi = 0;
    #pragma unroll
    for (int k = 1; k < Kd; ++k) {
        float v = ncb[(size_t)k * HWD + p];
        if (v > best) { best = v; bi = k; }
    }
    map[p] = (unsigned char)bi;
}

// ---------------------------------------------------------------------------
// fg_score: one block per box; count pixels where argmax == label.
// ---------------------------------------------------------------------------
__global__ __launch_bounds__(256) void k_fg(const unsigned char* __restrict__ map,
                                            const int* __restrict__ boxes,
                                            const int* __restrict__ labels,
                                            float* __restrict__ fg) {
    const int n = blockIdx.x;
    const int x0 = boxes[n * 4 + 0];
    const int y0 = boxes[n * 4 + 1];
    const int x1 = boxes[n * 4 + 2];
    const int y1 = boxes[n * 4 + 3];
    const int lab = labels[n];
    const int lane = threadIdx.x & 63;
    const int wv   = threadIdx.x >> 6;
    const int w = x1 - x0;

    int cnt = 0;
    for (int yy = y0 + wv; yy < y1; yy += 4) {
        if (lane < w)
            cnt += (map[yy * Wd + x0 + lane] == lab) ? 1 : 0;
    }
    #pragma unroll
    for (int d = 32; d; d >>= 1) cnt += __shfl_down(cnt, d);

    __shared__ int sred[4];
    if (lane == 0) sred[wv] = cnt;
    __syncthreads();
    if (threadIdx.x == 0) {
        int tot = sred[0] + sred[1] + sred[2] + sred[3];
        float area = (float)(w * (y1 - y0));
        fg[n] = (float)tot / area;
    }
}

extern "C" void kernel_launch(void* const* d_in, const int* in_sizes, int n_in,
                              void* d_out, int out_size, void* d_ws, size_t ws_size,
                              hipStream_t stream) {
    (void)in_sizes; (void)n_in; (void)out_size; (void)ws_size;

    const float* feature_map = (const float*)d_in[0];   // [256][512][512] f32
    const float* norm_cam_bg = (const float*)d_in[1];   // [21][512][512]  f32
    const int*   boxes       = (const int*)d_in[2];     // [2560][4] i32
    const int*   labels      = (const int*)d_in[3];     // [2560]    i32

    float* out_pool = (float*)d_out;                    // [2560][256]
    float* out_fg   = out_pool + (size_t)Nd * Cd;       // [2560]

    // d_ws layout (all rewritten every call; no state carried across calls)
    unsigned char* map      = (unsigned char*)d_ws;                    // 256 KB
    int*           ev_cnt   = (int*)((char*)d_ws + 262144);            // 512 int
    int*           ev_start = (int*)((char*)d_ws + 262144 + 2048);     // 513 int
    int*           ev_cur   = (int*)((char*)d_ws + 262144 + 6144);     // 512 int
    unsigned int*  ev_list  = (unsigned int*)((char*)d_ws + 262144 + 8192); // <=5120

    k_zero<<<1, 512, 0, stream>>>(ev_cnt);
    k_count<<<(Nd + 255) / 256, 256, 0, stream>>>(boxes, ev_cnt);
    k_scan<<<1, 512, 0, stream>>>(ev_cnt, ev_start, ev_cur);
    k_scatter<<<(Nd + 255) / 256, 256, 0, stream>>>(boxes, ev_cur, ev_list);
    k_argmax<<<HWD / 256, 256, 0, stream>>>(norm_cam_bg, map);
    k_ipool<<<Cd, 512, 0, stream>>>(feature_map, boxes, ev_start, ev_list, out_pool);
    k_fg<<<Nd, 256, 0, stream>>>(map, boxes, labels, out_fg);
}

// Round 4
// 144.000 us; speedup vs baseline: 2.0238x; 2.0238x over previous
//
#include <hip/hip_runtime.h>

#define HWD (512*512)
#define Wd 512
#define Hd 512
#define Cd 256
#define Kd 21
#define Nd 2560
#define NSTRIP 4
#define SROWS 128   // rows per strip

// ---------------------------------------------------------------------------
// Event-list build.  An "event" is a box edge at integral row r: at r = y1-1
// the box contributes +(S[r][x1-1]-S[r][x0-1]); at r = y0-1 (if y0>0) the
// negative.  Events bucketed per row.  ev = n (12b) | row<<12 (9b) | sign<<31.
// ---------------------------------------------------------------------------
__global__ __launch_bounds__(512) void k_zero(int* __restrict__ cnt) {
    cnt[threadIdx.x] = 0;
}

__global__ __launch_bounds__(256) void k_count(const int* __restrict__ boxes,
                                               int* __restrict__ cnt) {
    const int n = blockIdx.x * 256 + threadIdx.x;
    if (n >= Nd) return;
    const int y0 = boxes[n * 4 + 1];
    const int y1 = boxes[n * 4 + 3];
    if (y0 > 0) atomicAdd(&cnt[y0 - 1], 1);
    atomicAdd(&cnt[y1 - 1], 1);
}

__global__ __launch_bounds__(512) void k_scan(const int* __restrict__ cnt,
                                              int* __restrict__ start,
                                              int* __restrict__ cursor) {
    const int t = threadIdx.x, lane = t & 63, wv = t >> 6;
    const int v = cnt[t];
    int inc = v;
    #pragma unroll
    for (int d = 1; d < 64; d <<= 1) {
        int u = __shfl_up(inc, d);
        if (lane >= d) inc += u;
    }
    __shared__ int tt[8];
    if (lane == 63) tt[wv] = inc;
    __syncthreads();
    int off = 0;
    #pragma unroll
    for (int w = 0; w < 8; ++w)
        if (w < wv) off += tt[w];
    inc += off;
    start[t]  = inc - v;     // exclusive prefix
    cursor[t] = inc - v;
    if (t == 511) start[512] = inc;   // total
}

__global__ __launch_bounds__(256) void k_scatter(const int* __restrict__ boxes,
                                                 int* __restrict__ cursor,
                                                 unsigned int* __restrict__ ev) {
    const int n = blockIdx.x * 256 + threadIdx.x;
    if (n >= Nd) return;
    const int y0 = boxes[n * 4 + 1];
    const int y1 = boxes[n * 4 + 3];
    if (y0 > 0) {
        int r = y0 - 1;
        int p = atomicAdd(&cursor[r], 1);
        ev[p] = (unsigned int)n | ((unsigned int)r << 12) | 0x80000000u;
    }
    {
        int r = y1 - 1;
        int p = atomicAdd(&cursor[r], 1);
        ev[p] = (unsigned int)n | ((unsigned int)r << 12);
    }
}

// ---------------------------------------------------------------------------
// Fused strip-local integral + ROI corner consumption.
// Grid = 256 channels x 4 strips = 1024 blocks (4/CU, 32 waves/CU).
// Block streams its 128-row strip in 8-row slabs; thread owns column x.
//   - 8 independent wave-shfl row scans + cross-wave LDS offsets
//   - strip-LOCAL column accumulation (acc) -> integral slab S in LDS
//   - per-row events consume S into partial[n] (LDS); race-free: a box's two
//     events are >= 8 rows apart -> different slabs -> barrier-ordered
// End of strip: write column sums T[strip][x][c] (for cross-strip fix-up)
// and scatter flagged partials to pool_acc[strip][n][c] (pre-zeroed,
// non-atomic, unique writer per slot -> fully deterministic).
// Single-buffered S is safe: S-writes happen between sync1 and sync2;
// S-reads (events) between sync2 and the NEXT sync1.
// ---------------------------------------------------------------------------
__global__ __launch_bounds__(512) void k_ipool(const float* __restrict__ f,
                                               const int* __restrict__ boxes,
                                               const int* __restrict__ ev_start,
                                               const unsigned int* __restrict__ ev_list,
                                               float* __restrict__ pool_acc,
                                               float* __restrict__ T) {
    const int c     = blockIdx.x >> 2;
    const int strip = blockIdx.x & 3;
    const int x = threadIdx.x;
    const int lane = x & 63, wv = x >> 6;
    const float* F = f + (size_t)c * HWD + (size_t)strip * SROWS * Wd;

    __shared__ float S[8][512];            // 16 KB strip-local integral slab
    __shared__ float tot[8][8];            // wave totals per row
    __shared__ float partial[Nd];          // 10 KB per-box accumulated sum
    __shared__ unsigned int flags[Nd / 32];// 320 B touched-box bitmask

    for (int n = x; n < Nd; n += 512) partial[n] = 0.f;
    if (x < Nd / 32) flags[x] = 0u;
    // ordered before first event processing by sync1 below

    float acc = 0.f;
    float cur[8];
    #pragma unroll
    for (int j = 0; j < 8; ++j) cur[j] = F[(size_t)j * Wd + x];

    const int rbase = strip * SROWS;
    for (int yb = 0; yb < SROWS; yb += 8) {
        float nxt[8];
        const bool more = (yb + 8 < SROWS);
        if (more) {
            #pragma unroll
            for (int j = 0; j < 8; ++j) nxt[j] = F[(size_t)(yb + 8 + j) * Wd + x];
        }

        // 8 independent wave-inclusive scans (ILP across rows)
        float r[8];
        #pragma unroll
        for (int j = 0; j < 8; ++j) r[j] = cur[j];
        #pragma unroll
        for (int d = 1; d < 64; d <<= 1) {
            #pragma unroll
            for (int j = 0; j < 8; ++j) {
                float t = __shfl_up(r[j], d);
                if (lane >= d) r[j] += t;
            }
        }
        if (lane == 63) {
            #pragma unroll
            for (int j = 0; j < 8; ++j) tot[j][wv] = r[j];
        }
        __syncthreads();                               // sync1

        #pragma unroll
        for (int j = 0; j < 8; ++j) {
            float off = 0.f;
            #pragma unroll
            for (int w = 0; w < 8; ++w)
                if (w < wv) off += tot[j][w];
            acc += r[j] + off;
            S[j][x] = acc;
        }
        __syncthreads();                               // sync2

        // consume this slab's box-edge events (strip-local part)
        const int g0 = rbase + yb;
        const int e0 = ev_start[g0];
        const int e1 = ev_start[g0 + 8];
        for (int e = e0 + x; e < e1; e += 512) {
            const unsigned int ev = ev_list[e];
            const int n   = ev & 0xFFF;
            const int row = (ev >> 12) & 0x1FF;
            const int x0  = boxes[n * 4 + 0];
            const int x1  = boxes[n * 4 + 2];
            const float sx1 = S[row & 7][x1 - 1];
            const float sx0 = (x0 > 0) ? S[row & 7][x0 - 1] : 0.f;
            float d = sx1 - sx0;
            partial[n] += (ev & 0x80000000u) ? -d : d;
            atomicOr(&flags[n >> 5], 1u << (n & 31));
        }

        if (more) {
            #pragma unroll
            for (int j = 0; j < 8; ++j) cur[j] = nxt[j];
        }
    }

    // strip column sums for cross-strip fix-up (channel-last -> kernel B coalesced)
    T[((size_t)strip * Wd + x) * Cd + c] = acc;

    __syncthreads();
    for (int n = x; n < Nd; n += 512) {
        if (flags[n >> 5] & (1u << (n & 31)))
            pool_acc[((size_t)strip * Nd + n) * Cd + c] = partial[n];
    }
}

// ---------------------------------------------------------------------------
// Fix-up + finalize: pool[n][c] = (sum of strip partials + cross-strip T
// prefix terms for each event) / area.  Block = box, thread = channel.
// ---------------------------------------------------------------------------
__global__ __launch_bounds__(256) void k_pool2(const float* __restrict__ pool_acc,
                                               const float* __restrict__ T,
                                               const int* __restrict__ boxes,
                                               float* __restrict__ pool) {
    const int n = blockIdx.x;
    const int c = threadIdx.x;
    const int x0 = boxes[n * 4 + 0];
    const int y0 = boxes[n * 4 + 1];
    const int x1 = boxes[n * 4 + 2];
    const int y1 = boxes[n * 4 + 3];

    float v = 0.f;
    #pragma unroll
    for (int s = 0; s < NSTRIP; ++s)
        v += pool_acc[((size_t)s * Nd + n) * Cd + c];

    // + event at r = y1-1: add strips before it
    const int s1 = (y1 - 1) >> 7;
    for (int s = 0; s < s1; ++s) {
        v += T[((size_t)s * Wd + (x1 - 1)) * Cd + c];
        if (x0 > 0) v -= T[((size_t)s * Wd + (x0 - 1)) * Cd + c];
    }
    // - event at r = y0-1
    if (y0 > 0) {
        const int s0 = (y0 - 1) >> 7;
        for (int s = 0; s < s0; ++s) {
            v -= T[((size_t)s * Wd + (x1 - 1)) * Cd + c];
            if (x0 > 0) v += T[((size_t)s * Wd + (x0 - 1)) * Cd + c];
        }
    }

    const float area = (float)((x1 - x0) * (y1 - y0));
    pool[(size_t)n * Cd + c] = v / area;
}

// ---------------------------------------------------------------------------
// Argmax over K=21 classes per pixel -> u8 map.  First-max-wins (strict >).
// ---------------------------------------------------------------------------
__global__ __launch_bounds__(256) void k_argmax(const float* __restrict__ ncb,
                                                unsigned char* __restrict__ map) {
    const int p = blockIdx.x * 256 + threadIdx.x;
    float best = ncb[p];
    int bi = 0;
    #pragma unroll
    for (int k = 1; k < Kd; ++k) {
        float v = ncb[(size_t)k * HWD + p];
        if (v > best) { best = v; bi = k; }
    }
    map[p] = (unsigned char)bi;
}

// ---------------------------------------------------------------------------
// fg_score: one block per box; count pixels where argmax == label.
// ---------------------------------------------------------------------------
__global__ __launch_bounds__(256) void k_fg(const unsigned char* __restrict__ map,
                                            const int* __restrict__ boxes,
                                            const int* __restrict__ labels,
                                            float* __restrict__ fg) {
    const int n = blockIdx.x;
    const int x0 = boxes[n * 4 + 0];
    const int y0 = boxes[n * 4 + 1];
    const int x1 = boxes[n * 4 + 2];
    const int y1 = boxes[n * 4 + 3];
    const int lab = labels[n];
    const int lane = threadIdx.x & 63;
    const int wv   = threadIdx.x >> 6;
    const int w = x1 - x0;

    int cnt = 0;
    for (int yy = y0 + wv; yy < y1; yy += 4) {
        if (lane < w)
            cnt += (map[yy * Wd + x0 + lane] == lab) ? 1 : 0;
    }
    #pragma unroll
    for (int d = 32; d; d >>= 1) cnt += __shfl_down(cnt, d);

    __shared__ int sred[4];
    if (lane == 0) sred[wv] = cnt;
    __syncthreads();
    if (threadIdx.x == 0) {
        int tot = sred[0] + sred[1] + sred[2] + sred[3];
        float area = (float)(w * (y1 - y0));
        fg[n] = (float)tot / area;
    }
}

extern "C" void kernel_launch(void* const* d_in, const int* in_sizes, int n_in,
                              void* d_out, int out_size, void* d_ws, size_t ws_size,
                              hipStream_t stream) {
    (void)in_sizes; (void)n_in; (void)out_size; (void)ws_size;

    const float* feature_map = (const float*)d_in[0];   // [256][512][512] f32
    const float* norm_cam_bg = (const float*)d_in[1];   // [21][512][512]  f32
    const int*   boxes       = (const int*)d_in[2];     // [2560][4] i32
    const int*   labels      = (const int*)d_in[3];     // [2560]    i32

    float* out_pool = (float*)d_out;                    // [2560][256]
    float* out_fg   = out_pool + (size_t)Nd * Cd;       // [2560]

    // d_ws layout (all rewritten every call; no state carried across calls)
    char* ws = (char*)d_ws;
    unsigned char* map      = (unsigned char*)ws;                  // 256 KB
    int*           ev_cnt   = (int*)(ws + 262144);                 // 512 int
    int*           ev_start = (int*)(ws + 262144 + 4096);          // 513 int
    int*           ev_cur   = (int*)(ws + 262144 + 8192);          // 512 int
    unsigned int*  ev_list  = (unsigned int*)(ws + 262144 + 12288);// <=5120 u32
    float*         pool_acc = (float*)(ws + 294912);               // 4*2560*256 f32 = 10.5 MB
    float*         T        = (float*)(ws + 294912 + 10485760);    // 4*512*256 f32 = 2 MB

    hipMemsetAsync(pool_acc, 0, (size_t)NSTRIP * Nd * Cd * 4, stream);
    k_zero<<<1, 512, 0, stream>>>(ev_cnt);
    k_count<<<(Nd + 255) / 256, 256, 0, stream>>>(boxes, ev_cnt);
    k_scan<<<1, 512, 0, stream>>>(ev_cnt, ev_start, ev_cur);
    k_scatter<<<(Nd + 255) / 256, 256, 0, stream>>>(boxes, ev_cur, ev_list);
    k_argmax<<<HWD / 256, 256, 0, stream>>>(norm_cam_bg, map);
    k_ipool<<<Cd * NSTRIP, 512, 0, stream>>>(feature_map, boxes, ev_start, ev_list,
                                             pool_acc, T);
    k_pool2<<<Nd, 256, 0, stream>>>(pool_acc, T, boxes, out_pool);
    k_fg<<<Nd, 256, 0, stream>>>(map, boxes, labels, out_fg);
}

// Round 5
// 79.967 us; speedup vs baseline: 3.6444x; 1.8007x over previous
//
#include <hip/hip_runtime.h>

#define HWD (512*512)
#define Wd 512
#define Hd 512
#define Cd 256
#define Kd 21
#define Nd 2560
#define NSTRIP 4
#define SROWS 128   // rows per strip

// ---------------------------------------------------------------------------
// Event build, single block.  Event = box edge at integral row r: at r=y1-1
// contribute +(S[r][x1-1]-S[r][x0-1]); at r=y0-1 (if y0>0) the negative.
// Bucketed per row.  ev = n (12b) | row<<12 (9b) | sign<<31.
// ---------------------------------------------------------------------------
__global__ __launch_bounds__(512) void k_events(const int* __restrict__ boxes,
                                                int* __restrict__ ev_start,
                                                unsigned int* __restrict__ ev_list) {
    __shared__ int cnt[512];
    __shared__ int cur[512];
    __shared__ int tt[8];
    const int t = threadIdx.x, lane = t & 63, wv = t >> 6;
    cnt[t] = 0;
    __syncthreads();
    for (int n = t; n < Nd; n += 512) {
        const int y0 = boxes[n * 4 + 1];
        const int y1 = boxes[n * 4 + 3];
        if (y0 > 0) atomicAdd(&cnt[y0 - 1], 1);
        atomicAdd(&cnt[y1 - 1], 1);
    }
    __syncthreads();
    const int v = cnt[t];
    int inc = v;
    #pragma unroll
    for (int d = 1; d < 64; d <<= 1) {
        int u = __shfl_up(inc, d);
        if (lane >= d) inc += u;
    }
    if (lane == 63) tt[wv] = inc;
    __syncthreads();
    int off = 0;
    #pragma unroll
    for (int w = 0; w < 8; ++w) if (w < wv) off += tt[w];
    inc += off;
    cur[t] = inc - v;
    ev_start[t] = inc - v;
    if (t == 511) ev_start[512] = inc;
    __syncthreads();
    for (int n = t; n < Nd; n += 512) {
        const int y0 = boxes[n * 4 + 1];
        const int y1 = boxes[n * 4 + 3];
        if (y0 > 0) {
            const int r = y0 - 1;
            const int p = atomicAdd(&cur[r], 1);
            ev_list[p] = (unsigned)n | ((unsigned)r << 12) | 0x80000000u;
        }
        const int r = y1 - 1;
        const int p = atomicAdd(&cur[r], 1);
        ev_list[p] = (unsigned)n | ((unsigned)r << 12);
    }
}

// ---------------------------------------------------------------------------
// Fused strip-local integral + ROI corner consumption + cross-strip fold.
// Grid = 256 channels x 4 strips (4 blocks/CU, 32 waves/CU).  Per 8-row slab:
//   - wave wv scans row wv: float4x2 load (lane owns 8 cols), serial-8 +
//     single wave-shfl scan -> full 512-col row prefix, written to S[wv][:]
//   - column phase: thread t owns column t, in-place vertical accumulation
//   - events consume S (strip-local integral) into partial[] (LDS)
// End of strip: block's column-sum vector (colacc) is folded directly into
// boxes whose events lie in LATER strips -> no T array, no fix-up reads.
// pool_acc written [strip][c][n] = coalesced.  Race-free: a box's two events
// are >= 8 rows apart -> different slabs -> barrier-ordered; partial[n] final
// read is barrier-ordered; unique writer per pool_acc slot -> deterministic.
// ---------------------------------------------------------------------------
__global__ __launch_bounds__(512) void k_ipool(const float* __restrict__ f,
                                               const int* __restrict__ boxes,
                                               const int* __restrict__ ev_start,
                                               const unsigned int* __restrict__ ev_list,
                                               float* __restrict__ pool_acc) {
    const int c     = blockIdx.x >> 2;
    const int strip = blockIdx.x & 3;
    const int t = threadIdx.x;
    const int lane = t & 63, wv = t >> 6;
    const float* F = f + (size_t)c * HWD + (size_t)(strip * SROWS) * Wd;

    __shared__ float S[8][512];      // 16 KB slab (row-prefixes, then integral)
    __shared__ float partial[Nd];    // 10 KB per-box accumulated sum

    for (int n = t; n < Nd; n += 512) partial[n] = 0.f;
    // ordered before first event use by slab-0 barriers below

    float colacc = 0.f;              // thread t = column t vertical accumulator
    const float* rp = F + (size_t)wv * Wd + lane * 8;
    float4 a = *(const float4*)(rp);
    float4 b = *(const float4*)(rp + 4);

    for (int yb = 0; yb < SROWS; yb += 8) {
        const bool more = (yb + 8 < SROWS);
        float4 na, nb;
        if (more) {
            const float* np = F + (size_t)(yb + 8 + wv) * Wd + lane * 8;
            na = *(const float4*)(np);
            nb = *(const float4*)(np + 4);
        }

        // lane-serial scan of 8 + wave scan of lane totals = full row prefix
        float v0 = a.x, v1 = v0 + a.y, v2 = v1 + a.z, v3 = v2 + a.w;
        float v4 = v3 + b.x, v5 = v4 + b.y, v6 = v5 + b.z, v7 = v6 + b.w;
        float s = v7, xx = s;
        #pragma unroll
        for (int d = 1; d < 64; d <<= 1) {
            float u = __shfl_up(xx, d);
            if (lane >= d) xx += u;
        }
        const float off = xx - s;
        float4 o0 = { v0 + off, v1 + off, v2 + off, v3 + off };
        float4 o1 = { v4 + off, v5 + off, v6 + off, v7 + off };
        *(float4*)&S[wv][lane * 8]     = o0;
        *(float4*)&S[wv][lane * 8 + 4] = o1;
        __syncthreads();                           // row prefixes ready

        // vertical integration, in place (thread t only touches column t)
        #pragma unroll
        for (int j = 0; j < 8; ++j) {
            colacc += S[j][t];
            S[j][t] = colacc;
        }
        __syncthreads();                           // strip-local integral ready

        // consume this slab's box-edge events
        const int g0 = strip * SROWS + yb;
        const int e0 = ev_start[g0];
        const int e1 = ev_start[g0 + 8];
        for (int e = e0 + t; e < e1; e += 512) {
            const unsigned ev = ev_list[e];
            const int n  = ev & 0xFFF;
            const int r  = (ev >> 12) & 0x1FF;
            const int x0 = boxes[n * 4 + 0];
            const int x1 = boxes[n * 4 + 2];
            const float sx1 = S[r & 7][x1 - 1];
            const float sx0 = (x0 > 0) ? S[r & 7][x0 - 1] : 0.f;
            const float d = sx1 - sx0;
            partial[n] += (ev & 0x80000000u) ? -d : d;
        }
        __syncthreads();                           // events done before S reuse

        if (more) { a = na; b = nb; }
    }

    // cross-strip fold: this strip's column sums feed boxes whose events lie
    // in later strips (+ for the y1-1 event's strips, - for y0-1's).
    S[0][t] = colacc;
    __syncthreads();
    for (int n = t; n < Nd; n += 512) {
        const int x0 = boxes[n * 4 + 0];
        const int y0 = boxes[n * 4 + 1];
        const int x1 = boxes[n * 4 + 2];
        const int y1 = boxes[n * 4 + 3];
        float p = partial[n];
        const float tdiff = S[0][x1 - 1] - ((x0 > 0) ? S[0][x0 - 1] : 0.f);
        if (strip < ((y1 - 1) >> 7)) p += tdiff;
        if (y0 > 0 && strip < ((y0 - 1) >> 7)) p -= tdiff;
        pool_acc[((size_t)(strip * Cd + c)) * Nd + n] = p;   // coalesced
    }
}

// ---------------------------------------------------------------------------
// Finalize: pool[n][c] = (sum of 4 strip contributions) / area, with an LDS
// transpose so both the pool_acc reads ([c][n]) and pool writes ([n][c]) are
// coalesced.  80 blocks x 32 boxes.
// ---------------------------------------------------------------------------
__global__ __launch_bounds__(512) void k_pool2(const float* __restrict__ pool_acc,
                                               const int* __restrict__ boxes,
                                               float* __restrict__ pool) {
    __shared__ float P[32][257];     // +1 pad: conflict-free transpose
    __shared__ float rarea[32];
    const int t = threadIdx.x;
    const int n0 = blockIdx.x * 32;

    if (t < 32) {
        const int x0 = boxes[(n0 + t) * 4 + 0];
        const int y0 = boxes[(n0 + t) * 4 + 1];
        const int x1 = boxes[(n0 + t) * 4 + 2];
        const int y1 = boxes[(n0 + t) * 4 + 3];
        rarea[t] = 1.f / (float)((x1 - x0) * (y1 - y0));
    }

    const int ni = t & 31, ci = t >> 5;        // 16 c-lanes x 32 n
    #pragma unroll
    for (int co = 0; co < 16; ++co) {
        const int c = co * 16 + ci;
        float v = 0.f;
        #pragma unroll
        for (int s = 0; s < NSTRIP; ++s)
            v += pool_acc[((size_t)(s * Cd + c)) * Nd + n0 + ni];
        P[ni][c] = v;
    }
    __syncthreads();

    const int c = t & 255, nn = t >> 8;        // 2 n x 256 c
    #pragma unroll
    for (int no = 0; no < 16; ++no) {
        const int i = no * 2 + nn;
        pool[(size_t)(n0 + i) * Cd + c] = P[i][c] * rarea[i];
    }
}

// ---------------------------------------------------------------------------
// Argmax over K=21 classes per pixel -> u8 map.  First-max-wins (strict >).
// ---------------------------------------------------------------------------
__global__ __launch_bounds__(256) void k_argmax(const float* __restrict__ ncb,
                                                unsigned char* __restrict__ map) {
    const int p = blockIdx.x * 256 + threadIdx.x;
    float best = ncb[p];
    int bi = 0;
    #pragma unroll
    for (int k = 1; k < Kd; ++k) {
        float v = ncb[(size_t)k * HWD + p];
        if (v > best) { best = v; bi = k; }
    }
    map[p] = (unsigned char)bi;
}

// ---------------------------------------------------------------------------
// fg_score: one block per box; count pixels where argmax == label (map is
// L2-resident, 256 KB).  Exact integer count == reference one-hot integral.
// ---------------------------------------------------------------------------
__global__ __launch_bounds__(256) void k_fg(const unsigned char* __restrict__ map,
                                            const int* __restrict__ boxes,
                                            const int* __restrict__ labels,
                                            float* __restrict__ fg) {
    const int n = blockIdx.x;
    const int x0 = boxes[n * 4 + 0];
    const int y0 = boxes[n * 4 + 1];
    const int x1 = boxes[n * 4 + 2];
    const int y1 = boxes[n * 4 + 3];
    const int lab = labels[n];
    const int lane = threadIdx.x & 63;
    const int wv   = threadIdx.x >> 6;
    const int w = x1 - x0;

    int cnt = 0;
    for (int yy = y0 + wv; yy < y1; yy += 4) {
        if (lane < w)
            cnt += (map[yy * Wd + x0 + lane] == lab) ? 1 : 0;
    }
    #pragma unroll
    for (int d = 32; d; d >>= 1) cnt += __shfl_down(cnt, d);

    __shared__ int sred[4];
    if (lane == 0) sred[wv] = cnt;
    __syncthreads();
    if (threadIdx.x == 0) {
        int tot = sred[0] + sred[1] + sred[2] + sred[3];
        float area = (float)(w * (y1 - y0));
        fg[n] = (float)tot / area;
    }
}

extern "C" void kernel_launch(void* const* d_in, const int* in_sizes, int n_in,
                              void* d_out, int out_size, void* d_ws, size_t ws_size,
                              hipStream_t stream) {
    (void)in_sizes; (void)n_in; (void)out_size; (void)ws_size;

    const float* feature_map = (const float*)d_in[0];   // [256][512][512] f32
    const float* norm_cam_bg = (const float*)d_in[1];   // [21][512][512]  f32
    const int*   boxes       = (const int*)d_in[2];     // [2560][4] i32
    const int*   labels      = (const int*)d_in[3];     // [2560]    i32

    float* out_pool = (float*)d_out;                    // [2560][256]
    float* out_fg   = out_pool + (size_t)Nd * Cd;       // [2560]

    // d_ws layout (all rewritten every call; no state carried across calls)
    char* ws = (char*)d_ws;
    unsigned char* map      = (unsigned char*)ws;                   // 256 KB
    int*           ev_start = (int*)(ws + 262144);                  // 513 int
    unsigned int*  ev_list  = (unsigned int*)(ws + 266240);         // <=5120 u32
    float*         pool_acc = (float*)(ws + 286720);                // 4*256*2560 f32 = 10.5 MB

    k_events<<<1, 512, 0, stream>>>(boxes, ev_start, ev_list);
    k_argmax<<<HWD / 256, 256, 0, stream>>>(norm_cam_bg, map);
    k_ipool<<<Cd * NSTRIP, 512, 0, stream>>>(feature_map, boxes, ev_start, ev_list,
                                             pool_acc);
    k_pool2<<<Nd / 32, 512, 0, stream>>>(pool_acc, boxes, out_pool);
    k_fg<<<Nd, 256, 0, stream>>>(map, boxes, labels, out_fg);
}